// Round 12
// baseline (282.450 us; speedup 1.0000x reference)
//
#include <hip/hip_runtime.h>

typedef unsigned short ushort_t;
typedef unsigned int   uint_t;
typedef __attribute__((ext_vector_type(8))) short bf16x8;   // 8 bf16 in 4 VGPRs
typedef __attribute__((ext_vector_type(4))) float f32x4;    // MFMA accumulator

__device__ __forceinline__ ushort_t f2bf(float f) {
    union { float f; uint_t i; } x; x.f = f;
    uint_t i = x.i + 0x7fffu + ((x.i >> 16) & 1u);   // RNE
    return (ushort_t)(i >> 16);
}
__device__ __forceinline__ uint_t fbits(float f) {
    union { float f; uint_t i; } x; x.f = f;
    return x.i;
}
__device__ __forceinline__ void async16(const void* g, void* l) {
    __builtin_amdgcn_global_load_lds(
        (const __attribute__((address_space(1))) uint_t*)g,
        (__attribute__((address_space(3))) uint_t*)l, 16, 0, 0);
}

// ---------- prep: fp32 -> bf16 elementwise (4 elems/thread) ----------
__global__ __launch_bounds__(256) void conv_bf16(
    const float* __restrict__ in, ushort_t* __restrict__ outp)
{
    int i = (blockIdx.x * 256 + threadIdx.x) * 4;
    float4 v = *(const float4*)(in + i);
    uint_t a = (uint_t)f2bf(v.x) | ((uint_t)f2bf(v.y) << 16);
    uint_t b = (uint_t)f2bf(v.z) | ((uint_t)f2bf(v.w) << 16);
    uint2 st = { a, b };
    *(uint2*)(outp + i) = st;
}

// ---------- prep: fp32 [R][C] -> bf16 [C][R] (64x64 LDS tiles) ----------
__global__ __launch_bounds__(256) void transpose_conv(
    const float* __restrict__ in, ushort_t* __restrict__ outp, int R, int C)
{
    __shared__ ushort_t t[64][65];
    int r0 = blockIdx.y * 64, c0 = blockIdx.x * 64;
    int lr = threadIdx.x >> 4, lc = (threadIdx.x & 15) * 4;
#pragma unroll
    for (int rr = 0; rr < 4; ++rr) {
        float4 v = *(const float4*)(in + (size_t)(r0 + rr * 16 + lr) * C + c0 + lc);
        t[lc + 0][rr * 16 + lr] = f2bf(v.x);
        t[lc + 1][rr * 16 + lr] = f2bf(v.y);
        t[lc + 2][rr * 16 + lr] = f2bf(v.z);
        t[lc + 3][rr * 16 + lr] = f2bf(v.w);
    }
    __syncthreads();
    int oc = threadIdx.x >> 2, och = (threadIdx.x & 3) * 16;
    union { uint4 v[2]; ushort_t u[16]; } pk;
#pragma unroll
    for (int j = 0; j < 16; ++j) pk.u[j] = t[oc][och + j];
    uint4* dst = (uint4*)(outp + (size_t)(c0 + oc) * R + r0 + och);
    dst[0] = pk.v[0]; dst[1] = pk.v[1];
}

// ---------- prep: RoPE table, tab[t*32+i] = (cos, sin)(t * 10000^(-i/32)) ----------
__global__ __launch_bounds__(256) void rope_table_k(float2* __restrict__ tab)
{
    int idx = blockIdx.x * 256 + threadIdx.x;   // < 2048*32
    int t = idx >> 5, i = idx & 31;
    float freq = powf(10000.0f, -(float)i * (1.0f / 32.0f));
    float sn, cs;
    sincosf((float)t * freq, &sn, &cs);
    tab[idx] = make_float2(cs, sn);
}

// ---------- bf16 MFMA GEMM (128^2): kept for V (MODE 2 transposed epilogue) ----------
template <int MODE>
__global__ __launch_bounds__(256) void gemm_mfma(
    const ushort_t* __restrict__ A, const ushort_t* __restrict__ Bt,
    const float* __restrict__ bias, void* __restrict__ Cv,
    const float2* __restrict__ tab, int M, int N, int K, int coloff)
{
    __shared__ ushort_t As[128][64];
    __shared__ ushort_t Bs[128][64];
    const int tid = threadIdx.x;
    const int w = tid >> 6, lane = tid & 63, ln = lane & 15, quad = lane >> 4;
    const int wm = w >> 1, wn = w & 1;

    // XCD-bijective chunk swizzle of the block id
    const int lin = blockIdx.y * gridDim.x + blockIdx.x;
    const int per = (gridDim.x * gridDim.y) >> 3;   // nwg/8; all grids %8==0
    const int nid = (lin & 7) * per + (lin >> 3);
    const int bx = nid % gridDim.x, by = nid / gridDim.x;
    const int row0 = by * 128, col0 = bx * 128 + coloff;

    f32x4 acc[4][4] = {};

    const int swch = (lane & 7) ^ (lane >> 3);   // source chunk permutation
    const ushort_t* ga = A  + (size_t)(row0 + w * 8 + (lane >> 3)) * K + swch * 8;
    const ushort_t* gb = Bt + (size_t)(col0 + w * 8 + (lane >> 3)) * K + swch * 8;
    ushort_t* la = &As[w * 8][0];      // wave-uniform LDS bases
    ushort_t* lb = &Bs[w * 8][0];
    const int rch0 = ln & 7;           // read-side swizzle key

    for (int k0 = 0; k0 < K; k0 += 64) {
#pragma unroll
        for (int j = 0; j < 4; ++j) {
            async16(ga + (size_t)(j * 32) * K + k0, la + j * 32 * 64);
            async16(gb + (size_t)(j * 32) * K + k0, lb + j * 32 * 64);
        }
        __syncthreads();
#pragma unroll
        for (int kk = 0; kk < 2; ++kk) {
            int ch = ((kk * 4 + quad) ^ rch0) * 8;
            bf16x8 af[4], bfv[4];
#pragma unroll
            for (int mt = 0; mt < 4; ++mt)
                af[mt] = *(const bf16x8*)&As[wm * 64 + mt * 16 + ln][ch];
#pragma unroll
            for (int nt = 0; nt < 4; ++nt)
                bfv[nt] = *(const bf16x8*)&Bs[wn * 64 + nt * 16 + ln][ch];
#pragma unroll
            for (int mt = 0; mt < 4; ++mt)
#pragma unroll
                for (int nt = 0; nt < 4; ++nt) {
                    if (MODE == 2)   // original: D row=M(quad*4+r), col=N(ln)
                        acc[mt][nt] = __builtin_amdgcn_mfma_f32_16x16x32_bf16(
                            af[mt], bfv[nt], acc[mt][nt], 0, 0, 0);
                    else             // swapped: D row=N(quad*4+r), col=M(ln)
                        acc[mt][nt] = __builtin_amdgcn_mfma_f32_16x16x32_bf16(
                            bfv[nt], af[mt], acc[mt][nt], 0, 0, 0);
                }
        }
        __syncthreads();
    }

    if (MODE == 2) {
        // thread holds C[rows rr0..rr0+3][col c] = V[t0..t0+3][d] -> vtg[bh][d][t]
#pragma unroll
        for (int nt = 0; nt < 4; ++nt) {
            int c = col0 + wn * 64 + nt * 16 + ln;        // global col in [2048,3072)
            float bv = bias[c];
            int c2 = c - 2048;
            size_t vrow = ((size_t)(c2 >> 6)) * 64 + (c2 & 63);   // h*64+d (b added below)
#pragma unroll
            for (int mt = 0; mt < 4; ++mt) {
                int rr = row0 + wm * 64 + mt * 16 + quad * 4;
                int b = rr >> 11, t0 = rr & 2047;
                uint2 st;
                st.x = (uint_t)f2bf(acc[mt][nt][0] + bv)
                     | ((uint_t)f2bf(acc[mt][nt][1] + bv) << 16);
                st.y = (uint_t)f2bf(acc[mt][nt][2] + bv)
                     | ((uint_t)f2bf(acc[mt][nt][3] + bv) << 16);
                *(uint2*)((ushort_t*)Cv + ((size_t)b * 16 * 64 + vrow) * 2048 + t0) = st;
            }
        }
    } else {
        // swapped: thread holds C[row rr][cols c0..c0+3]
#pragma unroll
        for (int mt = 0; mt < 4; ++mt) {
            int rr = row0 + wm * 64 + mt * 16 + ln;
#pragma unroll
            for (int nt = 0; nt < 4; ++nt) {
                int c0 = col0 + wn * 64 + nt * 16 + quad * 4;
                float4 bv = *(const float4*)(bias + c0);
                float v0 = acc[mt][nt][0] + bv.x, v1 = acc[mt][nt][1] + bv.y;
                float v2 = acc[mt][nt][2] + bv.z, v3 = acc[mt][nt][3] + bv.w;
                if (MODE == 1) {
                    int i0 = (c0 & 63) >> 1;
                    const float2* trow = tab + (size_t)(rr & 2047) * 32;
                    float2 cs0 = trow[i0], cs1 = trow[i0 + 1];
                    float o0 = v0 * cs0.x - v1 * cs0.y;
                    float o1 = v1 * cs0.x + v0 * cs0.y;
                    float o2 = v2 * cs1.x - v3 * cs1.y;
                    float o3 = v3 * cs1.x + v2 * cs1.y;
                    uint2 st;
                    st.x = (uint_t)f2bf(o0) | ((uint_t)f2bf(o1) << 16);
                    st.y = (uint_t)f2bf(o2) | ((uint_t)f2bf(o3) << 16);
                    *(uint2*)((ushort_t*)Cv + (size_t)rr * N + c0) = st;
                } else {
                    float4 st = { v0, v1, v2, v3 };
                    *(float4*)((float*)Cv + (size_t)rr * N + c0) = st;
                }
            }
        }
    }
}

// ---------- 256x256-tile GEMM: q,k with fused RoPE ----------
// R11: + double-barrier phases (m201/T3 mechanism): all waves ds_read together
// -> s_barrier -> all waves MFMA together. The role-split is what lets setprio
// (T5) and the CU scheduler overlap the LDS and MFMA pipes (m218b: T5 pays
// ONLY on double-barrier phase schedules). Additive change: barriers only.
// (R8 BK=32 counted-vmcnt: REGRESSED, poisoned. R9 proj-256^2: REGRESSED.)
template <int MODE>
__global__ __launch_bounds__(512, 2) void gemm256(
    const ushort_t* __restrict__ A, const ushort_t* __restrict__ Bt,
    const float* __restrict__ bias, void* __restrict__ Cv,
    const float2* __restrict__ tab, int N)
{
    __shared__ ushort_t As[2][256][64];   // 64 KB
    __shared__ ushort_t Bs[2][256][64];   // 64 KB

    const int tid = threadIdx.x;
    const int w = tid >> 6, lane = tid & 63, ln = lane & 15, quad = lane >> 4;
    const int wm = w >> 2, wn = w & 3;                 // 2M x 4N waves

    const int lin = blockIdx.y * gridDim.x + blockIdx.x;
    const int per = (gridDim.x * gridDim.y) >> 3;
    const int nid = (lin & 7) * per + (lin >> 3);
    const int bx = nid % gridDim.x, by = nid / gridDim.x;
    const int row0 = by * 256, col0 = bx * 256;

    const int r6 = tid >> 3, c8 = tid & 7;             // staging row / chunk
    const int swch = c8 ^ (r6 & 7);                    // source chunk permutation
    const ushort_t* ga = A  + (size_t)(row0 + r6) * 1024 + swch * 8;
    const ushort_t* gb = Bt + (size_t)(col0 + r6) * 1024 + swch * 8;
    ushort_t* lau = &As[0][0][0] + tid * 8;            // lane-linear dest (16B/lane)
    ushort_t* lbu = &Bs[0][0][0] + tid * 8;
    const int rch0 = ln & 7;                           // read-side swizzle key

    f32x4 acc[8][4] = {};

    // prologue: stage K-tile 0 into buf 0 (8 loads), drain, barrier
#pragma unroll
    for (int j = 0; j < 4; ++j) {
        async16(ga + (size_t)(j * 64) * 1024, lau + j * 4096);
        async16(gb + (size_t)(j * 64) * 1024, lbu + j * 4096);
    }
    asm volatile("s_waitcnt vmcnt(0)" ::: "memory");
    __builtin_amdgcn_s_barrier();

#pragma unroll 2
    for (int k = 0; k < 16; ++k) {
        const int cur = k & 1;
        const int kn = (k < 15) ? k + 1 : k;           // last iter: restage (harmless)
        const size_t koff = (size_t)kn * 64;
#pragma unroll
        for (int j = 0; j < 4; ++j) {
            async16(ga + (size_t)(j * 64) * 1024 + koff, lau + (cur ^ 1) * 16384 + j * 4096);
            async16(gb + (size_t)(j * 64) * 1024 + koff, lbu + (cur ^ 1) * 16384 + j * 4096);
        }
        bf16x8 bf[4];
#pragma unroll
        for (int q = 0; q < 4; ++q) {
            const int kk = q >> 1, mh = q & 1;
            const int ch = ((kk * 4 + quad) ^ rch0) * 8;
            if (mh == 0) {                              // B frags reused across mh
#pragma unroll
                for (int nt = 0; nt < 4; ++nt)
                    bf[nt] = *(const bf16x8*)&Bs[cur][wn * 64 + nt * 16 + ln][ch];
            }
            bf16x8 af[4];
#pragma unroll
            for (int mt = 0; mt < 4; ++mt)
                af[mt] = *(const bf16x8*)&As[cur][mh * 128 + wm * 64 + mt * 16 + ln][ch];
            __builtin_amdgcn_s_barrier();               // role-split: reads | MFMA
            __builtin_amdgcn_s_setprio(1);
#pragma unroll
            for (int mt = 0; mt < 4; ++mt)
#pragma unroll
                for (int nt = 0; nt < 4; ++nt)
                    acc[mh * 4 + mt][nt] = __builtin_amdgcn_mfma_f32_16x16x32_bf16(
                        bf[nt], af[mt], acc[mh * 4 + mt][nt], 0, 0, 0);
            __builtin_amdgcn_s_setprio(0);
            if (q == 3)   // group end: next tile landed; all waves sync before swap
                asm volatile("s_waitcnt vmcnt(0)" ::: "memory");
            __builtin_amdgcn_s_barrier();
        }
    }

    // epilogue: swapped C-layout, thread holds C[rr][c0..c0+3]
#pragma unroll
    for (int mg = 0; mg < 8; ++mg) {
        const int rr = row0 + (mg >> 2) * 128 + wm * 64 + (mg & 3) * 16 + ln;
        const float2* trow = tab + (size_t)(rr & 2047) * 32;   // unused if MODE==0
#pragma unroll
        for (int nt = 0; nt < 4; ++nt) {
            const int c0 = col0 + wn * 64 + nt * 16 + quad * 4;
            float4 bv = *(const float4*)(bias + c0);
            float v0 = acc[mg][nt][0] + bv.x, v1 = acc[mg][nt][1] + bv.y;
            float v2 = acc[mg][nt][2] + bv.z, v3 = acc[mg][nt][3] + bv.w;
            if (MODE == 1) {
                const int i0 = (c0 & 63) >> 1;
                float2 cs0 = trow[i0], cs1 = trow[i0 + 1];
                float o0 = v0 * cs0.x - v1 * cs0.y;
                float o1 = v1 * cs0.x + v0 * cs0.y;
                float o2 = v2 * cs1.x - v3 * cs1.y;
                float o3 = v3 * cs1.x + v2 * cs1.y;
                uint2 st;
                st.x = (uint_t)f2bf(o0) | ((uint_t)f2bf(o1) << 16);
                st.y = (uint_t)f2bf(o2) | ((uint_t)f2bf(o3) << 16);
                *(uint2*)((ushort_t*)Cv + (size_t)rr * N + c0) = st;
            } else {
                float4 st = { v0, v1, v2, v3 };
                *(float4*)((float*)Cv + (size_t)rr * N + c0) = st;
            }
        }
    }
}

// ---------- 256x128-tile GEMM for proj (M=8192, N=1024, K=1024) ----------
// R11: + double-barrier phases (same T3 mechanism as gemm256).
__global__ __launch_bounds__(512, 2) void gemm_proj(
    const ushort_t* __restrict__ A, const ushort_t* __restrict__ Bt,
    const float* __restrict__ bias, float* __restrict__ C)
{
    __shared__ ushort_t As[2][256][64];   // 64 KB
    __shared__ ushort_t Bs[2][128][64];   // 32 KB

    const int tid = threadIdx.x;
    const int w = tid >> 6, lane = tid & 63, ln = lane & 15, quad = lane >> 4;
    const int wm = w >> 1, wn = w & 1;                 // 4M x 2N waves

    // XCD swizzle over 256 blocks (grid 8 x 32): each XCD gets 4 row-panels
    const int lin = blockIdx.y * 8 + blockIdx.x;
    const int nid = (lin & 7) * 32 + (lin >> 3);
    const int bx = nid & 7, by = nid >> 3;
    const int row0 = by * 256, col0 = bx * 128;

    const int r6 = tid >> 3, c8 = tid & 7;             // staging row / chunk
    const int swch = c8 ^ (r6 & 7);                    // (r6+j*64)&7 == r6&7
    const ushort_t* ga = A  + (size_t)(row0 + r6) * 1024 + swch * 8;
    const ushort_t* gb = Bt + (size_t)(col0 + r6) * 1024 + swch * 8;
    ushort_t* lau = &As[0][0][0] + tid * 8;            // lane-linear dest
    ushort_t* lbu = &Bs[0][0][0] + tid * 8;
    const int rch0 = ln & 7;

    f32x4 acc[4][4] = {};

    // prologue: K-tile 0 -> buf 0 (A: 4 loads rows r6+j*64; B: 2 loads)
#pragma unroll
    for (int j = 0; j < 4; ++j)
        async16(ga + (size_t)(j * 64) * 1024, lau + j * 4096);
#pragma unroll
    for (int j = 0; j < 2; ++j)
        async16(gb + (size_t)(j * 64) * 1024, lbu + j * 4096);
    asm volatile("s_waitcnt vmcnt(0)" ::: "memory");
    __builtin_amdgcn_s_barrier();

#pragma unroll 2
    for (int k = 0; k < 16; ++k) {
        const int cur = k & 1;
        const int kn = (k < 15) ? k + 1 : k;           // last iter: restage (harmless)
        const size_t koff = (size_t)kn * 64;
#pragma unroll
        for (int j = 0; j < 4; ++j)
            async16(ga + (size_t)(j * 64) * 1024 + koff, lau + (cur ^ 1) * 16384 + j * 4096);
#pragma unroll
        for (int j = 0; j < 2; ++j)
            async16(gb + (size_t)(j * 64) * 1024 + koff, lbu + (cur ^ 1) * 8192 + j * 4096);
#pragma unroll
        for (int kk = 0; kk < 2; ++kk) {
            const int ch = ((kk * 4 + quad) ^ rch0) * 8;
            bf16x8 bf[4], af[4];
#pragma unroll
            for (int nt = 0; nt < 4; ++nt)
                bf[nt] = *(const bf16x8*)&Bs[cur][wn * 64 + nt * 16 + ln][ch];
#pragma unroll
            for (int mt = 0; mt < 4; ++mt)
                af[mt] = *(const bf16x8*)&As[cur][wm * 64 + mt * 16 + ln][ch];
            __builtin_amdgcn_s_barrier();               // role-split: reads | MFMA
            __builtin_amdgcn_s_setprio(1);
#pragma unroll
            for (int mt = 0; mt < 4; ++mt)
#pragma unroll
                for (int nt = 0; nt < 4; ++nt)
                    acc[mt][nt] = __builtin_amdgcn_mfma_f32_16x16x32_bf16(
                        bf[nt], af[mt], acc[mt][nt], 0, 0, 0);
            __builtin_amdgcn_s_setprio(0);
            if (kk == 1)   // tile end: next tile landed; sync before buffer swap
                asm volatile("s_waitcnt vmcnt(0)" ::: "memory");
            __builtin_amdgcn_s_barrier();
        }
    }

    // epilogue: swapped orientation, thread holds C[rr][c0..c0+3], fp32 + bias
#pragma unroll
    for (int mt = 0; mt < 4; ++mt) {
        const int rr = row0 + wm * 64 + mt * 16 + ln;
#pragma unroll
        for (int nt = 0; nt < 4; ++nt) {
            const int c0 = col0 + wn * 64 + nt * 16 + quad * 4;
            float4 bv = *(const float4*)(bias + c0);
            float4 st = { acc[mt][nt][0] + bv.x, acc[mt][nt][1] + bv.y,
                          acc[mt][nt][2] + bv.z, acc[mt][nt][3] + bv.w };
            *(float4*)(C + (size_t)rr * 1024 + c0) = st;
        }
    }
}

// ---------- flash attention v9: raw v_exp_f32 + v_perm pack (NO inline asm in P path) ----------
__global__ __launch_bounds__(512, 4) void attn_mfma(
    const ushort_t* __restrict__ qkv, const ushort_t* __restrict__ vtg,
    ushort_t* __restrict__ outp)
{
    __shared__ ushort_t Ks[2][64][64];    // roped K [t][d], chunk-swizzled, dbuf
    __shared__ ushort_t Vts[2][64][64];   // V^T [d][t], chunk-swizzled, dbuf
    __shared__ ushort_t Ps[8][16][72];    // per-wave P bounce [q][t] (stride 72)

    const int tid = threadIdx.x;
    const int w = tid >> 6, lane = tid & 63, ln = lane & 15, quad = lane >> 4;
    const int bh = blockIdx.x, qt = blockIdx.y, b = bh >> 4, h = bh & 15;
    const size_t base = (size_t)b * 2048 * 3072 + h * 64;

    bf16x8 af[2][2];
#pragma unroll
    for (int s = 0; s < 2; ++s)
#pragma unroll
        for (int kk = 0; kk < 2; ++kk)
            af[s][kk] = *(const bf16x8*)(qkv + base
                + (size_t)(qt * 256 + w * 32 + s * 16 + ln) * 3072 + kk * 32 + quad * 8);

    bf16x8 ones;
#pragma unroll
    for (int j = 0; j < 8; ++j) ones[j] = (short)0x3F80;   // bf16 1.0

    f32x4 oaccT[2][4] = {};
    f32x4 oneacc[2] = {};
    const float SC = 0.125f * 1.44269504f;

    const int swch = (lane & 7) ^ (lane >> 3);
    const ushort_t* kg = qkv + base + 1024 + (size_t)(lane >> 3) * 3072 + swch * 8;
    const ushort_t* vg = vtg + ((size_t)bh * 64 + (lane >> 3)) * 2048 + swch * 8;
    const int rch0 = ln & 7;
    const int r8 = w * 8;

    async16(kg + (size_t)r8 * 3072, &Ks[0][r8][0]);
    async16(vg + (size_t)r8 * 2048, &Vts[0][r8][0]);
    asm volatile("s_waitcnt vmcnt(0)" ::: "memory");
    __builtin_amdgcn_s_barrier();

    int cur = 0;
    for (int kt = 0; kt < 32; ++kt) {
        if (kt < 31) {
            async16(kg + (size_t)((kt + 1) * 64 + r8) * 3072, &Ks[cur ^ 1][r8][0]);
            async16(vg + (size_t)r8 * 2048 + (kt + 1) * 64, &Vts[cur ^ 1][r8][0]);
        }

        bf16x8 kf[2][4], vf[2][4];
#pragma unroll
        for (int kk = 0; kk < 2; ++kk) {
            int ch = ((kk * 4 + quad) ^ rch0) * 8;
#pragma unroll
            for (int nt = 0; nt < 4; ++nt) {
                kf[kk][nt] = *(const bf16x8*)&Ks[cur][nt * 16 + ln][ch];
                vf[kk][nt] = *(const bf16x8*)&Vts[cur][nt * 16 + ln][ch];
            }
        }

#pragma unroll
        for (int s = 0; s < 2; ++s) {
            f32x4 sacc[4] = {};
#pragma unroll
            for (int kk = 0; kk < 2; ++kk)
#pragma unroll
                for (int nt = 0; nt < 4; ++nt)
                    sacc[nt] = __builtin_amdgcn_mfma_f32_16x16x32_bf16(
                        kf[kk][nt], af[s][kk], sacc[nt], 0, 0, 0);

            if (s == 1)
                asm volatile("s_waitcnt lgkmcnt(0)" ::: "memory");
#pragma unroll
            for (int nt = 0; nt < 4; ++nt) {
                float e0 = __builtin_amdgcn_exp2f(fmaf(sacc[nt][0], SC, -24.0f));
                float e1 = __builtin_amdgcn_exp2f(fmaf(sacc[nt][1], SC, -24.0f));
                float e2 = __builtin_amdgcn_exp2f(fmaf(sacc[nt][2], SC, -24.0f));
                float e3 = __builtin_amdgcn_exp2f(fmaf(sacc[nt][3], SC, -24.0f));
                uint2 pk;
                pk.x = __builtin_amdgcn_perm(fbits(e1), fbits(e0), 0x07060302u);
                pk.y = __builtin_amdgcn_perm(fbits(e3), fbits(e2), 0x07060302u);
                *(uint2*)&Ps[w][ln][nt * 16 + quad * 4] = pk;
            }
            asm volatile("s_waitcnt lgkmcnt(0)" ::: "memory");

#pragma unroll
            for (int kk = 0; kk < 2; ++kk) {
                bf16x8 pf = *(const bf16x8*)&Ps[w][ln][kk * 32 + quad * 8];
                oneacc[s] = __builtin_amdgcn_mfma_f32_16x16x32_bf16(
                    ones, pf, oneacc[s], 0, 0, 0);
#pragma unroll
                for (int nt = 0; nt < 4; ++nt)
                    oaccT[s][nt] = __builtin_amdgcn_mfma_f32_16x16x32_bf16(
                        vf[kk][nt], pf, oaccT[s][nt], 0, 0, 0);
            }
        }

        asm volatile("s_waitcnt vmcnt(0) lgkmcnt(0)" ::: "memory");
        __builtin_amdgcn_s_barrier();
        cur ^= 1;
    }

#pragma unroll
    for (int s = 0; s < 2; ++s) {
        float linv = 1.0f / oneacc[s][0];
        size_t row = (size_t)b * 2048 + qt * 256 + w * 32 + s * 16 + ln;
#pragma unroll
        for (int nt = 0; nt < 4; ++nt) {
            uint2 st;
            st.x = (uint_t)f2bf(oaccT[s][nt][0] * linv)
                 | ((uint_t)f2bf(oaccT[s][nt][1] * linv) << 16);
            st.y = (uint_t)f2bf(oaccT[s][nt][2] * linv)
                 | ((uint_t)f2bf(oaccT[s][nt][3] * linv) << 16);
            *(uint2*)(outp + row * 1024 + h * 64 + nt * 16 + quad * 4) = st;
        }
    }
}

// ---------- launch ----------
extern "C" void kernel_launch(void* const* d_in, const int* in_sizes, int n_in,
                              void* d_out, int out_size, void* d_ws, size_t ws_size,
                              hipStream_t stream)
{
    (void)in_sizes; (void)n_in; (void)out_size; (void)ws_size;

    const float* x      = (const float*)d_in[0];   // [8192,1024]
    const float* w_qkv  = (const float*)d_in[1];   // [1024,3072]
    const float* b_qkv  = (const float*)d_in[2];   // [3072]
    const float* w_proj = (const float*)d_in[3];   // [1024,1024]
    const float* b_proj = (const float*)d_in[4];   // [1024]
    float*       out    = (float*)d_out;           // [8192,1024]

    ushort_t* x_bf    = (ushort_t*)d_ws;                       // 8192*1024
    ushort_t* wqkvT   = x_bf    + (size_t)8192 * 1024;         // [3072][1024]
    ushort_t* wprojT  = wqkvT   + (size_t)3072 * 1024;         // [1024][1024]
    ushort_t* qkv_bf  = wprojT  + (size_t)1024 * 1024;         // [8192][3072] (q,k roped)
    ushort_t* attn_bf = qkv_bf  + (size_t)8192 * 3072;         // [8192][1024]
    ushort_t* vtg     = attn_bf + (size_t)8192 * 1024;         // [64 bh][64 d][2048 t]
    float2*   tab     = (float2*)(vtg + (size_t)64 * 64 * 2048);   // [2048*32]

    conv_bf16<<<8192, 256, 0, stream>>>(x, x_bf);
    transpose_conv<<<dim3(48, 16), 256, 0, stream>>>(w_qkv, wqkvT, 1024, 3072);
    transpose_conv<<<dim3(16, 16), 256, 0, stream>>>(w_proj, wprojT, 1024, 1024);
    rope_table_k<<<256, 256, 0, stream>>>(tab);

    // q,k columns [0,2048): 256^2 pipeline + double-barrier phases, fused RoPE
    gemm256<1><<<dim3(8, 32), 512, 0, stream>>>(
        x_bf, wqkvT, b_qkv, qkv_bf, tab, 3072);

    // v columns [2048,3072): 128^2, original orientation, transposed write to vtg
    gemm_mfma<2><<<dim3(8, 64), 256, 0, stream>>>(
        x_bf, wqkvT, b_qkv, vtg, nullptr, 8192, 3072, 1024, 2048);

    // grid (bh=64, qt=8): same-bh blocks land on one XCD (id % 8 == bh % 8)
    attn_mfma<<<dim3(64, 8), 512, 0, stream>>>(qkv_bf, vtg, attn_bf);

    // proj: 256x128 tile (256 blocks, all CUs) + double-barrier phases
    gemm_proj<<<dim3(8, 32), 512, 0, stream>>>(attn_bf, wprojT, b_proj, out);
}

// Round 13
// 278.421 us; speedup vs baseline: 1.0145x; 1.0145x over previous
//
#include <hip/hip_runtime.h>

typedef unsigned short ushort_t;
typedef unsigned int   uint_t;
typedef __attribute__((ext_vector_type(8))) short bf16x8;   // 8 bf16 in 4 VGPRs
typedef __attribute__((ext_vector_type(4))) float f32x4;    // MFMA accumulator

__device__ __forceinline__ ushort_t f2bf(float f) {
    union { float f; uint_t i; } x; x.f = f;
    uint_t i = x.i + 0x7fffu + ((x.i >> 16) & 1u);   // RNE
    return (ushort_t)(i >> 16);
}
__device__ __forceinline__ uint_t fbits(float f) {
    union { float f; uint_t i; } x; x.f = f;
    return x.i;
}
__device__ __forceinline__ void async16(const void* g, void* l) {
    __builtin_amdgcn_global_load_lds(
        (const __attribute__((address_space(1))) uint_t*)g,
        (__attribute__((address_space(3))) uint_t*)l, 16, 0, 0);
}

// ---------- prep: fp32 -> bf16 elementwise (4 elems/thread) ----------
__global__ __launch_bounds__(256) void conv_bf16(
    const float* __restrict__ in, ushort_t* __restrict__ outp)
{
    int i = (blockIdx.x * 256 + threadIdx.x) * 4;
    float4 v = *(const float4*)(in + i);
    uint_t a = (uint_t)f2bf(v.x) | ((uint_t)f2bf(v.y) << 16);
    uint_t b = (uint_t)f2bf(v.z) | ((uint_t)f2bf(v.w) << 16);
    uint2 st = { a, b };
    *(uint2*)(outp + i) = st;
}

// ---------- prep: fp32 [R][C] -> bf16 [C][R] (64x64 LDS tiles) ----------
__global__ __launch_bounds__(256) void transpose_conv(
    const float* __restrict__ in, ushort_t* __restrict__ outp, int R, int C)
{
    __shared__ ushort_t t[64][65];
    int r0 = blockIdx.y * 64, c0 = blockIdx.x * 64;
    int lr = threadIdx.x >> 4, lc = (threadIdx.x & 15) * 4;
#pragma unroll
    for (int rr = 0; rr < 4; ++rr) {
        float4 v = *(const float4*)(in + (size_t)(r0 + rr * 16 + lr) * C + c0 + lc);
        t[lc + 0][rr * 16 + lr] = f2bf(v.x);
        t[lc + 1][rr * 16 + lr] = f2bf(v.y);
        t[lc + 2][rr * 16 + lr] = f2bf(v.z);
        t[lc + 3][rr * 16 + lr] = f2bf(v.w);
    }
    __syncthreads();
    int oc = threadIdx.x >> 2, och = (threadIdx.x & 3) * 16;
    union { uint4 v[2]; ushort_t u[16]; } pk;
#pragma unroll
    for (int j = 0; j < 16; ++j) pk.u[j] = t[oc][och + j];
    uint4* dst = (uint4*)(outp + (size_t)(c0 + oc) * R + r0 + och);
    dst[0] = pk.v[0]; dst[1] = pk.v[1];
}

// ---------- prep: RoPE table, tab[t*32+i] = (cos, sin)(t * 10000^(-i/32)) ----------
__global__ __launch_bounds__(256) void rope_table_k(float2* __restrict__ tab)
{
    int idx = blockIdx.x * 256 + threadIdx.x;   // < 2048*32
    int t = idx >> 5, i = idx & 31;
    float freq = powf(10000.0f, -(float)i * (1.0f / 32.0f));
    float sn, cs;
    sincosf((float)t * freq, &sn, &cs);
    tab[idx] = make_float2(cs, sn);
}

// ---------- bf16 MFMA GEMM (128^2): kept for V (MODE 2 transposed epilogue) ----------
template <int MODE>
__global__ __launch_bounds__(256) void gemm_mfma(
    const ushort_t* __restrict__ A, const ushort_t* __restrict__ Bt,
    const float* __restrict__ bias, void* __restrict__ Cv,
    const float2* __restrict__ tab, int M, int N, int K, int coloff)
{
    __shared__ ushort_t As[128][64];
    __shared__ ushort_t Bs[128][64];
    const int tid = threadIdx.x;
    const int w = tid >> 6, lane = tid & 63, ln = lane & 15, quad = lane >> 4;
    const int wm = w >> 1, wn = w & 1;

    // XCD-bijective chunk swizzle of the block id
    const int lin = blockIdx.y * gridDim.x + blockIdx.x;
    const int per = (gridDim.x * gridDim.y) >> 3;   // nwg/8; all grids %8==0
    const int nid = (lin & 7) * per + (lin >> 3);
    const int bx = nid % gridDim.x, by = nid / gridDim.x;
    const int row0 = by * 128, col0 = bx * 128 + coloff;

    f32x4 acc[4][4] = {};

    const int swch = (lane & 7) ^ (lane >> 3);   // source chunk permutation
    const ushort_t* ga = A  + (size_t)(row0 + w * 8 + (lane >> 3)) * K + swch * 8;
    const ushort_t* gb = Bt + (size_t)(col0 + w * 8 + (lane >> 3)) * K + swch * 8;
    ushort_t* la = &As[w * 8][0];      // wave-uniform LDS bases
    ushort_t* lb = &Bs[w * 8][0];
    const int rch0 = ln & 7;           // read-side swizzle key

    for (int k0 = 0; k0 < K; k0 += 64) {
#pragma unroll
        for (int j = 0; j < 4; ++j) {
            async16(ga + (size_t)(j * 32) * K + k0, la + j * 32 * 64);
            async16(gb + (size_t)(j * 32) * K + k0, lb + j * 32 * 64);
        }
        __syncthreads();
#pragma unroll
        for (int kk = 0; kk < 2; ++kk) {
            int ch = ((kk * 4 + quad) ^ rch0) * 8;
            bf16x8 af[4], bfv[4];
#pragma unroll
            for (int mt = 0; mt < 4; ++mt)
                af[mt] = *(const bf16x8*)&As[wm * 64 + mt * 16 + ln][ch];
#pragma unroll
            for (int nt = 0; nt < 4; ++nt)
                bfv[nt] = *(const bf16x8*)&Bs[wn * 64 + nt * 16 + ln][ch];
#pragma unroll
            for (int mt = 0; mt < 4; ++mt)
#pragma unroll
                for (int nt = 0; nt < 4; ++nt) {
                    if (MODE == 2)   // original: D row=M(quad*4+r), col=N(ln)
                        acc[mt][nt] = __builtin_amdgcn_mfma_f32_16x16x32_bf16(
                            af[mt], bfv[nt], acc[mt][nt], 0, 0, 0);
                    else             // swapped: D row=N(quad*4+r), col=M(ln)
                        acc[mt][nt] = __builtin_amdgcn_mfma_f32_16x16x32_bf16(
                            bfv[nt], af[mt], acc[mt][nt], 0, 0, 0);
                }
        }
        __syncthreads();
    }

    if (MODE == 2) {
        // thread holds C[rows rr0..rr0+3][col c] = V[t0..t0+3][d] -> vtg[bh][d][t]
#pragma unroll
        for (int nt = 0; nt < 4; ++nt) {
            int c = col0 + wn * 64 + nt * 16 + ln;        // global col in [2048,3072)
            float bv = bias[c];
            int c2 = c - 2048;
            size_t vrow = ((size_t)(c2 >> 6)) * 64 + (c2 & 63);   // h*64+d (b added below)
#pragma unroll
            for (int mt = 0; mt < 4; ++mt) {
                int rr = row0 + wm * 64 + mt * 16 + quad * 4;
                int b = rr >> 11, t0 = rr & 2047;
                uint2 st;
                st.x = (uint_t)f2bf(acc[mt][nt][0] + bv)
                     | ((uint_t)f2bf(acc[mt][nt][1] + bv) << 16);
                st.y = (uint_t)f2bf(acc[mt][nt][2] + bv)
                     | ((uint_t)f2bf(acc[mt][nt][3] + bv) << 16);
                *(uint2*)((ushort_t*)Cv + ((size_t)b * 16 * 64 + vrow) * 2048 + t0) = st;
            }
        }
    } else {
        // swapped: thread holds C[row rr][cols c0..c0+3]
#pragma unroll
        for (int mt = 0; mt < 4; ++mt) {
            int rr = row0 + wm * 64 + mt * 16 + ln;
#pragma unroll
            for (int nt = 0; nt < 4; ++nt) {
                int c0 = col0 + wn * 64 + nt * 16 + quad * 4;
                float4 bv = *(const float4*)(bias + c0);
                float v0 = acc[mt][nt][0] + bv.x, v1 = acc[mt][nt][1] + bv.y;
                float v2 = acc[mt][nt][2] + bv.z, v3 = acc[mt][nt][3] + bv.w;
                if (MODE == 1) {
                    int i0 = (c0 & 63) >> 1;
                    const float2* trow = tab + (size_t)(rr & 2047) * 32;
                    float2 cs0 = trow[i0], cs1 = trow[i0 + 1];
                    float o0 = v0 * cs0.x - v1 * cs0.y;
                    float o1 = v1 * cs0.x + v0 * cs0.y;
                    float o2 = v2 * cs1.x - v3 * cs1.y;
                    float o3 = v3 * cs1.x + v2 * cs1.y;
                    uint2 st;
                    st.x = (uint_t)f2bf(o0) | ((uint_t)f2bf(o1) << 16);
                    st.y = (uint_t)f2bf(o2) | ((uint_t)f2bf(o3) << 16);
                    *(uint2*)((ushort_t*)Cv + (size_t)rr * N + c0) = st;
                } else {
                    float4 st = { v0, v1, v2, v3 };
                    *(float4*)((float*)Cv + (size_t)rr * N + c0) = st;
                }
            }
        }
    }
}

// ---------- 256x256-tile GEMM (R7-verified structure): q,k with fused RoPE ----------
// BK=64, 2-buffer, 4 phases/{ds_read, setprio(1), 16 MFMA, setprio(0), barrier},
// one vmcnt(0) drain per K-tile. Structure-family ledger (all single-variable):
//   R8  BK=32 counted-vmcnt 3-buf:  REGRESSED +8us (halved MFMA/barrier)
//   R9  proj at 256^2:              REGRESSED +11us (128 blocks = half CUs)
//   R10 proj at 256x128:            NULL
//   R11/R12 double-barrier phases:  NULL (+3us, within noise)
// -> R7 structure is the measured optimum of this family; frozen.
template <int MODE>
__global__ __launch_bounds__(512, 2) void gemm256(
    const ushort_t* __restrict__ A, const ushort_t* __restrict__ Bt,
    const float* __restrict__ bias, void* __restrict__ Cv,
    const float2* __restrict__ tab, int N)
{
    __shared__ ushort_t As[2][256][64];   // 64 KB
    __shared__ ushort_t Bs[2][256][64];   // 64 KB

    const int tid = threadIdx.x;
    const int w = tid >> 6, lane = tid & 63, ln = lane & 15, quad = lane >> 4;
    const int wm = w >> 2, wn = w & 3;                 // 2M x 4N waves

    const int lin = blockIdx.y * gridDim.x + blockIdx.x;
    const int per = (gridDim.x * gridDim.y) >> 3;
    const int nid = (lin & 7) * per + (lin >> 3);
    const int bx = nid % gridDim.x, by = nid / gridDim.x;
    const int row0 = by * 256, col0 = bx * 256;

    const int r6 = tid >> 3, c8 = tid & 7;             // staging row / chunk
    const int swch = c8 ^ (r6 & 7);                    // source chunk permutation
    const ushort_t* ga = A  + (size_t)(row0 + r6) * 1024 + swch * 8;
    const ushort_t* gb = Bt + (size_t)(col0 + r6) * 1024 + swch * 8;
    ushort_t* lau = &As[0][0][0] + tid * 8;            // lane-linear dest (16B/lane)
    ushort_t* lbu = &Bs[0][0][0] + tid * 8;
    const int rch0 = ln & 7;                           // read-side swizzle key

    f32x4 acc[8][4] = {};

    // prologue: stage K-tile 0 into buf 0 (8 loads), drain, barrier
#pragma unroll
    for (int j = 0; j < 4; ++j) {
        async16(ga + (size_t)(j * 64) * 1024, lau + j * 4096);
        async16(gb + (size_t)(j * 64) * 1024, lbu + j * 4096);
    }
    asm volatile("s_waitcnt vmcnt(0)" ::: "memory");
    __builtin_amdgcn_s_barrier();

#pragma unroll 2
    for (int k = 0; k < 16; ++k) {
        const int cur = k & 1;
        const int kn = (k < 15) ? k + 1 : k;           // last iter: restage (harmless)
        const size_t koff = (size_t)kn * 64;
        // stage next K-tile into buf cur^1; lands during this group's 4 phases
#pragma unroll
        for (int j = 0; j < 4; ++j) {
            async16(ga + (size_t)(j * 64) * 1024 + koff, lau + (cur ^ 1) * 16384 + j * 4096);
            async16(gb + (size_t)(j * 64) * 1024 + koff, lbu + (cur ^ 1) * 16384 + j * 4096);
        }
        bf16x8 bf[4];
#pragma unroll
        for (int q = 0; q < 4; ++q) {
            const int kk = q >> 1, mh = q & 1;
            const int ch = ((kk * 4 + quad) ^ rch0) * 8;
            if (mh == 0) {                              // B frags reused across mh
#pragma unroll
                for (int nt = 0; nt < 4; ++nt)
                    bf[nt] = *(const bf16x8*)&Bs[cur][wn * 64 + nt * 16 + ln][ch];
            }
            bf16x8 af[4];
#pragma unroll
            for (int mt = 0; mt < 4; ++mt)
                af[mt] = *(const bf16x8*)&As[cur][mh * 128 + wm * 64 + mt * 16 + ln][ch];
            __builtin_amdgcn_s_setprio(1);
#pragma unroll
            for (int mt = 0; mt < 4; ++mt)
#pragma unroll
                for (int nt = 0; nt < 4; ++nt)
                    acc[mh * 4 + mt][nt] = __builtin_amdgcn_mfma_f32_16x16x32_bf16(
                        bf[nt], af[mt], acc[mh * 4 + mt][nt], 0, 0, 0);
            __builtin_amdgcn_s_setprio(0);
            if (q == 3)   // group end: next tile landed; all waves sync before swap
                asm volatile("s_waitcnt vmcnt(0)" ::: "memory");
            __builtin_amdgcn_s_barrier();
        }
    }

    // epilogue: swapped C-layout, thread holds C[rr][c0..c0+3]
#pragma unroll
    for (int mg = 0; mg < 8; ++mg) {
        const int rr = row0 + (mg >> 2) * 128 + wm * 64 + (mg & 3) * 16 + ln;
        const float2* trow = tab + (size_t)(rr & 2047) * 32;   // unused if MODE==0
#pragma unroll
        for (int nt = 0; nt < 4; ++nt) {
            const int c0 = col0 + wn * 64 + nt * 16 + quad * 4;
            float4 bv = *(const float4*)(bias + c0);
            float v0 = acc[mg][nt][0] + bv.x, v1 = acc[mg][nt][1] + bv.y;
            float v2 = acc[mg][nt][2] + bv.z, v3 = acc[mg][nt][3] + bv.w;
            if (MODE == 1) {
                const int i0 = (c0 & 63) >> 1;
                float2 cs0 = trow[i0], cs1 = trow[i0 + 1];
                float o0 = v0 * cs0.x - v1 * cs0.y;
                float o1 = v1 * cs0.x + v0 * cs0.y;
                float o2 = v2 * cs1.x - v3 * cs1.y;
                float o3 = v3 * cs1.x + v2 * cs1.y;
                uint2 st;
                st.x = (uint_t)f2bf(o0) | ((uint_t)f2bf(o1) << 16);
                st.y = (uint_t)f2bf(o2) | ((uint_t)f2bf(o3) << 16);
                *(uint2*)((ushort_t*)Cv + (size_t)rr * N + c0) = st;
            } else {
                float4 st = { v0, v1, v2, v3 };
                *(float4*)((float*)Cv + (size_t)rr * N + c0) = st;
            }
        }
    }
}

// ---------- 256x128-tile GEMM for proj (M=8192, N=1024, K=1024) ----------
// 256 blocks (all CUs), LDS 96KB dbuf, waves 4M x 2N, per-wave 64x64.
// Same phase schedule as gemm256 (R10-measured config).
__global__ __launch_bounds__(512, 2) void gemm_proj(
    const ushort_t* __restrict__ A, const ushort_t* __restrict__ Bt,
    const float* __restrict__ bias, float* __restrict__ C)
{
    __shared__ ushort_t As[2][256][64];   // 64 KB
    __shared__ ushort_t Bs[2][128][64];   // 32 KB

    const int tid = threadIdx.x;
    const int w = tid >> 6, lane = tid & 63, ln = lane & 15, quad = lane >> 4;
    const int wm = w >> 1, wn = w & 1;                 // 4M x 2N waves

    // XCD swizzle over 256 blocks (grid 8 x 32): each XCD gets 4 row-panels
    const int lin = blockIdx.y * 8 + blockIdx.x;
    const int nid = (lin & 7) * 32 + (lin >> 3);
    const int bx = nid & 7, by = nid >> 3;
    const int row0 = by * 256, col0 = bx * 128;

    const int r6 = tid >> 3, c8 = tid & 7;             // staging row / chunk
    const int swch = c8 ^ (r6 & 7);                    // (r6+j*64)&7 == r6&7
    const ushort_t* ga = A  + (size_t)(row0 + r6) * 1024 + swch * 8;
    const ushort_t* gb = Bt + (size_t)(col0 + r6) * 1024 + swch * 8;
    ushort_t* lau = &As[0][0][0] + tid * 8;            // lane-linear dest
    ushort_t* lbu = &Bs[0][0][0] + tid * 8;
    const int rch0 = ln & 7;

    f32x4 acc[4][4] = {};

    // prologue: K-tile 0 -> buf 0 (A: 4 loads rows r6+j*64; B: 2 loads)
#pragma unroll
    for (int j = 0; j < 4; ++j)
        async16(ga + (size_t)(j * 64) * 1024, lau + j * 4096);
#pragma unroll
    for (int j = 0; j < 2; ++j)
        async16(gb + (size_t)(j * 64) * 1024, lbu + j * 4096);
    asm volatile("s_waitcnt vmcnt(0)" ::: "memory");
    __builtin_amdgcn_s_barrier();

#pragma unroll 2
    for (int k = 0; k < 16; ++k) {
        const int cur = k & 1;
        const int kn = (k < 15) ? k + 1 : k;           // last iter: restage (harmless)
        const size_t koff = (size_t)kn * 64;
#pragma unroll
        for (int j = 0; j < 4; ++j)
            async16(ga + (size_t)(j * 64) * 1024 + koff, lau + (cur ^ 1) * 16384 + j * 4096);
#pragma unroll
        for (int j = 0; j < 2; ++j)
            async16(gb + (size_t)(j * 64) * 1024 + koff, lbu + (cur ^ 1) * 8192 + j * 4096);
#pragma unroll
        for (int kk = 0; kk < 2; ++kk) {
            const int ch = ((kk * 4 + quad) ^ rch0) * 8;
            bf16x8 bf[4], af[4];
#pragma unroll
            for (int nt = 0; nt < 4; ++nt)
                bf[nt] = *(const bf16x8*)&Bs[cur][wn * 64 + nt * 16 + ln][ch];
#pragma unroll
            for (int mt = 0; mt < 4; ++mt)
                af[mt] = *(const bf16x8*)&As[cur][wm * 64 + mt * 16 + ln][ch];
            __builtin_amdgcn_s_setprio(1);
#pragma unroll
            for (int mt = 0; mt < 4; ++mt)
#pragma unroll
                for (int nt = 0; nt < 4; ++nt)
                    acc[mt][nt] = __builtin_amdgcn_mfma_f32_16x16x32_bf16(
                        bf[nt], af[mt], acc[mt][nt], 0, 0, 0);
            __builtin_amdgcn_s_setprio(0);
            if (kk == 1)   // tile end: next tile landed; sync before buffer swap
                asm volatile("s_waitcnt vmcnt(0)" ::: "memory");
            __builtin_amdgcn_s_barrier();
        }
    }

    // epilogue: swapped orientation, thread holds C[rr][c0..c0+3], fp32 + bias
#pragma unroll
    for (int mt = 0; mt < 4; ++mt) {
        const int rr = row0 + wm * 64 + mt * 16 + ln;
#pragma unroll
        for (int nt = 0; nt < 4; ++nt) {
            const int c0 = col0 + wn * 64 + nt * 16 + quad * 4;
            float4 bv = *(const float4*)(bias + c0);
            float4 st = { acc[mt][nt][0] + bv.x, acc[mt][nt][1] + bv.y,
                          acc[mt][nt][2] + bv.z, acc[mt][nt][3] + bv.w };
            *(float4*)(C + (size_t)rr * 1024 + c0) = st;
        }
    }
}

// ---------- flash attention v9: raw v_exp_f32 + v_perm pack (NO inline asm in P path) ----------
// Near its structural floor: MfmaUtil 35% = 31.9us MFMA (matches 68.7GF x 18/16
// / 2.5PF exactly); VALU+TRANS ~37us vs ~30us softmax minimum (32 exp2 + 32 fma
// + 8 perm per kt-wave, irreducible for exact softmax).
__global__ __launch_bounds__(512, 4) void attn_mfma(
    const ushort_t* __restrict__ qkv, const ushort_t* __restrict__ vtg,
    ushort_t* __restrict__ outp)
{
    __shared__ ushort_t Ks[2][64][64];    // roped K [t][d], chunk-swizzled, dbuf
    __shared__ ushort_t Vts[2][64][64];   // V^T [d][t], chunk-swizzled, dbuf
    __shared__ ushort_t Ps[8][16][72];    // per-wave P bounce [q][t] (stride 72)

    const int tid = threadIdx.x;
    const int w = tid >> 6, lane = tid & 63, ln = lane & 15, quad = lane >> 4;
    const int bh = blockIdx.x, qt = blockIdx.y, b = bh >> 4, h = bh & 15;
    const size_t base = (size_t)b * 2048 * 3072 + h * 64;

    bf16x8 af[2][2];
#pragma unroll
    for (int s = 0; s < 2; ++s)
#pragma unroll
        for (int kk = 0; kk < 2; ++kk)
            af[s][kk] = *(const bf16x8*)(qkv + base
                + (size_t)(qt * 256 + w * 32 + s * 16 + ln) * 3072 + kk * 32 + quad * 8);

    bf16x8 ones;
#pragma unroll
    for (int j = 0; j < 8; ++j) ones[j] = (short)0x3F80;   // bf16 1.0

    f32x4 oaccT[2][4] = {};
    f32x4 oneacc[2] = {};
    const float SC = 0.125f * 1.44269504f;

    const int swch = (lane & 7) ^ (lane >> 3);
    const ushort_t* kg = qkv + base + 1024 + (size_t)(lane >> 3) * 3072 + swch * 8;
    const ushort_t* vg = vtg + ((size_t)bh * 64 + (lane >> 3)) * 2048 + swch * 8;
    const int rch0 = ln & 7;
    const int r8 = w * 8;

    async16(kg + (size_t)r8 * 3072, &Ks[0][r8][0]);
    async16(vg + (size_t)r8 * 2048, &Vts[0][r8][0]);
    asm volatile("s_waitcnt vmcnt(0)" ::: "memory");
    __builtin_amdgcn_s_barrier();

    int cur = 0;
    for (int kt = 0; kt < 32; ++kt) {
        if (kt < 31) {
            async16(kg + (size_t)((kt + 1) * 64 + r8) * 3072, &Ks[cur ^ 1][r8][0]);
            async16(vg + (size_t)r8 * 2048 + (kt + 1) * 64, &Vts[cur ^ 1][r8][0]);
        }

        bf16x8 kf[2][4], vf[2][4];
#pragma unroll
        for (int kk = 0; kk < 2; ++kk) {
            int ch = ((kk * 4 + quad) ^ rch0) * 8;
#pragma unroll
            for (int nt = 0; nt < 4; ++nt) {
                kf[kk][nt] = *(const bf16x8*)&Ks[cur][nt * 16 + ln][ch];
                vf[kk][nt] = *(const bf16x8*)&Vts[cur][nt * 16 + ln][ch];
            }
        }

#pragma unroll
        for (int s = 0; s < 2; ++s) {
            f32x4 sacc[4] = {};
#pragma unroll
            for (int kk = 0; kk < 2; ++kk)
#pragma unroll
                for (int nt = 0; nt < 4; ++nt)
                    sacc[nt] = __builtin_amdgcn_mfma_f32_16x16x32_bf16(
                        kf[kk][nt], af[s][kk], sacc[nt], 0, 0, 0);

            if (s == 1)
                asm volatile("s_waitcnt lgkmcnt(0)" ::: "memory");
#pragma unroll
            for (int nt = 0; nt < 4; ++nt) {
                float e0 = __builtin_amdgcn_exp2f(fmaf(sacc[nt][0], SC, -24.0f));
                float e1 = __builtin_amdgcn_exp2f(fmaf(sacc[nt][1], SC, -24.0f));
                float e2 = __builtin_amdgcn_exp2f(fmaf(sacc[nt][2], SC, -24.0f));
                float e3 = __builtin_amdgcn_exp2f(fmaf(sacc[nt][3], SC, -24.0f));
                uint2 pk;
                pk.x = __builtin_amdgcn_perm(fbits(e1), fbits(e0), 0x07060302u);
                pk.y = __builtin_amdgcn_perm(fbits(e3), fbits(e2), 0x07060302u);
                *(uint2*)&Ps[w][ln][nt * 16 + quad * 4] = pk;
            }
            asm volatile("s_waitcnt lgkmcnt(0)" ::: "memory");

#pragma unroll
            for (int kk = 0; kk < 2; ++kk) {
                bf16x8 pf = *(const bf16x8*)&Ps[w][ln][kk * 32 + quad * 8];
                oneacc[s] = __builtin_amdgcn_mfma_f32_16x16x32_bf16(
                    ones, pf, oneacc[s], 0, 0, 0);
#pragma unroll
                for (int nt = 0; nt < 4; ++nt)
                    oaccT[s][nt] = __builtin_amdgcn_mfma_f32_16x16x32_bf16(
                        vf[kk][nt], pf, oaccT[s][nt], 0, 0, 0);
            }
        }

        asm volatile("s_waitcnt vmcnt(0) lgkmcnt(0)" ::: "memory");
        __builtin_amdgcn_s_barrier();
        cur ^= 1;
    }

#pragma unroll
    for (int s = 0; s < 2; ++s) {
        float linv = 1.0f / oneacc[s][0];
        size_t row = (size_t)b * 2048 + qt * 256 + w * 32 + s * 16 + ln;
#pragma unroll
        for (int nt = 0; nt < 4; ++nt) {
            uint2 st;
            st.x = (uint_t)f2bf(oaccT[s][nt][0] * linv)
                 | ((uint_t)f2bf(oaccT[s][nt][1] * linv) << 16);
            st.y = (uint_t)f2bf(oaccT[s][nt][2] * linv)
                 | ((uint_t)f2bf(oaccT[s][nt][3] * linv) << 16);
            *(uint2*)(outp + row * 1024 + h * 64 + nt * 16 + quad * 4) = st;
        }
    }
}

// ---------- launch ----------
extern "C" void kernel_launch(void* const* d_in, const int* in_sizes, int n_in,
                              void* d_out, int out_size, void* d_ws, size_t ws_size,
                              hipStream_t stream)
{
    (void)in_sizes; (void)n_in; (void)out_size; (void)ws_size;

    const float* x      = (const float*)d_in[0];   // [8192,1024]
    const float* w_qkv  = (const float*)d_in[1];   // [1024,3072]
    const float* b_qkv  = (const float*)d_in[2];   // [3072]
    const float* w_proj = (const float*)d_in[3];   // [1024,1024]
    const float* b_proj = (const float*)d_in[4];   // [1024]
    float*       out    = (float*)d_out;           // [8192,1024]

    ushort_t* x_bf    = (ushort_t*)d_ws;                       // 8192*1024
    ushort_t* wqkvT   = x_bf    + (size_t)8192 * 1024;         // [3072][1024]
    ushort_t* wprojT  = wqkvT   + (size_t)3072 * 1024;         // [1024][1024]
    ushort_t* qkv_bf  = wprojT  + (size_t)1024 * 1024;         // [8192][3072] (q,k roped)
    ushort_t* attn_bf = qkv_bf  + (size_t)8192 * 3072;         // [8192][1024]
    ushort_t* vtg     = attn_bf + (size_t)8192 * 1024;         // [64 bh][64 d][2048 t]
    float2*   tab     = (float2*)(vtg + (size_t)64 * 64 * 2048);   // [2048*32]

    conv_bf16<<<8192, 256, 0, stream>>>(x, x_bf);
    transpose_conv<<<dim3(48, 16), 256, 0, stream>>>(w_qkv, wqkvT, 1024, 3072);
    transpose_conv<<<dim3(16, 16), 256, 0, stream>>>(w_proj, wprojT, 1024, 1024);
    rope_table_k<<<256, 256, 0, stream>>>(tab);

    // q,k columns [0,2048): 256^2 R7-verified pipeline, fused RoPE
    gemm256<1><<<dim3(8, 32), 512, 0, stream>>>(
        x_bf, wqkvT, b_qkv, qkv_bf, tab, 3072);

    // v columns [2048,3072): 128^2, original orientation, transposed write to vtg
    gemm_mfma<2><<<dim3(8, 64), 256, 0, stream>>>(
        x_bf, wqkvT, b_qkv, vtg, nullptr, 8192, 3072, 1024, 2048);

    // grid (bh=64, qt=8): same-bh blocks land on one XCD (id % 8 == bh % 8)
    attn_mfma<<<dim3(64, 8), 512, 0, stream>>>(qkv_bf, vtg, attn_bf);

    // proj: 256x128 tile, 256 blocks (all CUs), deep-pipelined
    gemm_proj<<<dim3(8, 32), 512, 0, stream>>>(attn_bf, wprojT, b_proj, out);
}